// Round 6
// baseline (53.911 us; speedup 1.0000x reference)
//
#include <hip/hip_runtime.h>
#include <hip/hip_fp16.h>

// QuantLinear: out[16][11008] = x[16][4096] . dequant(weight_q[11008][4096])^T + bias
// dequant: w = scale[o][i/128] * ((wq & 255) - zero[o][i/128]), group = 128.
// Harness promotes fp16 tensors to fp32 -> x/scale/zero/bias are float*.
// Memory-bound: weight stream 180.4 MB; box demonstrates ~7 TB/s (fill dispatches)
// -> ~27 us floor. Round-2 single-kernel (688 blk, 10.75 waves/CU) = 51.2 us
// (~3.6 TB/s). Theory: grid-capped memory-level parallelism. Round-5 change:
// split-K x2 -> 1376 blocks (21.5 waves/CU), partials in d_ws, tiny reduce
// kernel adds bias. No atomics (round-1 lesson).

typedef _Float16 v8hf __attribute__((ext_vector_type(8)));
typedef float v4f __attribute__((ext_vector_type(4)));

#define O_DIM 11008
#define I_DIM 4096
#define NGROUP 32   // I_DIM / 128

// Block b = (o-tile ot = b>>1, K-half kc = b&1). 4 waves split the K-half into
// 4 groups each (group = 128 i's). Partial 16x16 f32 tile -> ws[b*256 + row*16 + c].
__global__ __launch_bounds__(256) void qgemm_part(const float* __restrict__ x,
                                                  const int* __restrict__ wq,
                                                  const float* __restrict__ scale,
                                                  const float* __restrict__ zero,
                                                  float* __restrict__ ws) {
    __shared__ float red[4][256];

    const int b   = blockIdx.x;    // 0..1375
    const int ot  = b >> 1;        // o-tile 0..687
    const int kc  = b & 1;         // K half
    const int tid = threadIdx.x;
    const int w   = tid >> 6;      // wave 0..3
    const int l   = tid & 63;
    const int col = l & 15;        // A-row = x-row / B-col = o (within tile)
    const int kb  = l >> 4;        // k sub-block 0..3
    const int o   = ot * 16 + col;

    const int*   __restrict__ wrow = wq + (size_t)o * I_DIM;
    const float* __restrict__ xrow = x  + (size_t)col * I_DIM;

    v4f acc = {0.f, 0.f, 0.f, 0.f};

    // Wave w handles scale-groups kc*16 + w*4 + [0,4) = 512 k's.
#pragma unroll 2
    for (int gi = 0; gi < 4; ++gi) {
        const int g = kc * 16 + w * 4 + gi;
        const float s   = scale[o * NGROUP + g];
        const float z   = zero [o * NGROUP + g];
        const float nzs = -z * s;
#pragma unroll
        for (int ks = 0; ks < 4; ++ks) {
            const int i0 = g * 128 + ks * 32 + kb * 8;   // this lane's 8 k's
            const int4   q0 = *(const int4*)  (wrow + i0);
            const int4   q1 = *(const int4*)  (wrow + i0 + 4);
            const float4 x0 = *(const float4*)(xrow + i0);
            const float4 x1 = *(const float4*)(xrow + i0 + 4);
            v8hf a;
            a[0] = (_Float16)x0.x; a[1] = (_Float16)x0.y;
            a[2] = (_Float16)x0.z; a[3] = (_Float16)x0.w;
            a[4] = (_Float16)x1.x; a[5] = (_Float16)x1.y;
            a[6] = (_Float16)x1.z; a[7] = (_Float16)x1.w;
            // B-frag: same (lane,j)->k mapping as A => internal permutation cancels.
            v8hf bf;
            bf[0] = (_Float16)((float)(q0.x & 255) * s + nzs);
            bf[1] = (_Float16)((float)(q0.y & 255) * s + nzs);
            bf[2] = (_Float16)((float)(q0.z & 255) * s + nzs);
            bf[3] = (_Float16)((float)(q0.w & 255) * s + nzs);
            bf[4] = (_Float16)((float)(q1.x & 255) * s + nzs);
            bf[5] = (_Float16)((float)(q1.y & 255) * s + nzs);
            bf[6] = (_Float16)((float)(q1.z & 255) * s + nzs);
            bf[7] = (_Float16)((float)(q1.w & 255) * s + nzs);
            acc = __builtin_amdgcn_mfma_f32_16x16x32_f16(a, bf, acc, 0, 0, 0);
        }
    }

    // Cross-wave reduce. acc[r] = tile element (row=(l>>4)*4+r, col=l&15).
    *(v4f*)&red[w][l * 4] = acc;   // lane-contiguous 16B stores, conflict-free
    __syncthreads();

    const int t   = tid;
    const float sum = red[0][t] + red[1][t] + red[2][t] + red[3][t];
    const int l2  = t >> 2;                 // original lane
    const int r   = t & 3;                  // acc register index
    const int row = (l2 >> 4) * 4 + r;      // x-row 0..15
    const int c   = l2 & 15;                // col within tile
    ws[(size_t)b * 256 + row * 16 + c] = sum;   // partial, no bias
}

// Sum the 2 K-half partials + bias -> out. 688 blocks x 256 = 176128 threads.
__global__ __launch_bounds__(256) void qreduce(const float* __restrict__ ws,
                                               const float* __restrict__ bias,
                                               float* __restrict__ out) {
    const int t   = blockIdx.x * 256 + threadIdx.x;  // < 16*11008
    const int oc  = t % O_DIM;
    const int row = t / O_DIM;
    const int ot  = oc >> 4;
    const int c   = oc & 15;
    const size_t base = (size_t)ot * 512 + row * 16 + c;  // block pair (ot*2, ot*2+1)
    out[t] = ws[base] + ws[base + 256] + bias[oc];
}

extern "C" void kernel_launch(void* const* d_in, const int* in_sizes, int n_in,
                              void* d_out, int out_size, void* d_ws, size_t ws_size,
                              hipStream_t stream) {
    const float* x   = (const float*)d_in[0];
    const int*   wqp = (const int*)  d_in[1];
    const float* sc  = (const float*)d_in[2];
    const float* zp  = (const float*)d_in[3];
    const float* bp  = (const float*)d_in[4];
    float* out = (float*)d_out;
    float* ws  = (float*)d_ws;     // 1376*256*4 B = 1.41 MB partials

    qgemm_part<<<1376, 256, 0, stream>>>(x, wqp, sc, zp, ws);
    qreduce<<<688, 256, 0, stream>>>(ws, bp, out);
}